// Round 1
// baseline (3445.524 us; speedup 1.0000x reference)
//
#include <hip/hip_runtime.h>
#include <math.h>

// ---------------------------------------------------------------------------
// MultiStreamCNN: two conv streams (3->32->64 w/ relu+maxpool2), concat,
// fuse conv 3x3 (128->128) + relu + global mean, det 1x1 conv, sigmoid + NMS.
// All fp32 (no fp32-input MFMA on CDNA4; bf16 risks the binary `keep` output).
// ---------------------------------------------------------------------------

#define B_ 8

// ---------- Kernel A: conv3x3 (3->32) + bias + relu + maxpool2 --------------
// in x: (8,3,512,512), out: (8,32,256,256). Block = 16x16 pooled pixels.
__global__ __launch_bounds__(256) void conv1_pool(
    const float* __restrict__ x, const float* __restrict__ w,
    const float* __restrict__ bias, float* __restrict__ out)
{
    __shared__ float s[3 * 34 * 34];
    const int b = blockIdx.z;
    const int tileX = blockIdx.x, tileY = blockIdx.y;
    const int tid = threadIdx.x;
    const int tx = tid & 15, ty = tid >> 4;
    const int ih0 = tileY * 32 - 1, iw0 = tileX * 32 - 1;

    for (int i = tid; i < 3 * 34 * 34; i += 256) {
        int c = i / 1156, r = i % 1156;
        int y = r / 34, xx = r % 34;
        int ih = ih0 + y, iw = iw0 + xx;
        float v = 0.f;
        if (ih >= 0 && ih < 512 && iw >= 0 && iw < 512)
            v = x[((b * 3 + c) * 512 + ih) * 512 + iw];
        s[i] = v;
    }
    __syncthreads();

    // Each thread: 4x4x3 input patch in registers (covers its 2x2 conv window)
    float in[3][4][4];
#pragma unroll
    for (int c = 0; c < 3; ++c)
#pragma unroll
        for (int dy = 0; dy < 4; ++dy)
#pragma unroll
            for (int dx = 0; dx < 4; ++dx)
                in[c][dy][dx] = s[c * 1156 + (2 * ty + dy) * 34 + (2 * tx + dx)];

    const int oh = tileY * 16 + ty, ow = tileX * 16 + tx;
    for (int oc = 0; oc < 32; ++oc) {
        const float bv = bias[oc];
        float m = -INFINITY;
#pragma unroll
        for (int py = 0; py < 2; ++py)
#pragma unroll
            for (int px = 0; px < 2; ++px) {
                float a = bv;
#pragma unroll
                for (int c = 0; c < 3; ++c)
#pragma unroll
                    for (int ky = 0; ky < 3; ++ky)
#pragma unroll
                        for (int kx = 0; kx < 3; ++kx)
                            a = fmaf(w[((oc * 3 + c) * 3 + ky) * 3 + kx],
                                     in[c][py + ky][px + kx], a);
                m = fmaxf(m, a);
            }
        m = fmaxf(m, 0.f);  // max(relu(...)) == relu(max(...))
        out[((b * 32 + oc) * 256 + oh) * 256 + ow] = m;
    }
}

// ---------- Kernel B: conv3x3 (32->64) + bias + relu + maxpool2 -------------
// in: (8,32,256,256), out: (8,64,128,128). Block = 16x16 CONV pixels (8x8 pooled).
__global__ __launch_bounds__(256) void conv2_pool(
    const float* __restrict__ in, const float* __restrict__ w,
    const float* __restrict__ bias, float* __restrict__ out)
{
    __shared__ float s[2 * 324];  // two input channels of 18x18
    const int b = blockIdx.z;
    const int tileX = blockIdx.x, tileY = blockIdx.y;
    const int tid = threadIdx.x;
    const int tx = tid & 15, ty = tid >> 4;
    const int y0 = tileY * 16 - 1, x0 = tileX * 16 - 1;

    float acc[64];
#pragma unroll
    for (int oc = 0; oc < 64; ++oc) acc[oc] = 0.f;

    for (int ic = 0; ic < 32; ic += 2) {
        __syncthreads();
        for (int i = tid; i < 648; i += 256) {
            int sub = (i >= 324) ? 1 : 0;
            int r = i - sub * 324;
            int y = r / 18, xx = r % 18;
            int ih = y0 + y, iw = x0 + xx;
            float v = 0.f;
            if (ih >= 0 && ih < 256 && iw >= 0 && iw < 256)
                v = in[((b * 32 + ic + sub) * 256 + ih) * 256 + iw];
            s[i] = v;
        }
        __syncthreads();

#pragma unroll
        for (int sub = 0; sub < 2; ++sub) {
            float p[3][3];
#pragma unroll
            for (int dy = 0; dy < 3; ++dy)
#pragma unroll
                for (int dx = 0; dx < 3; ++dx)
                    p[dy][dx] = s[sub * 324 + (ty + dy) * 18 + tx + dx];
#pragma unroll
            for (int oc = 0; oc < 64; ++oc) {
                const float* wp = &w[((oc * 32 + ic + sub) * 3) * 3];
                float a = acc[oc];
#pragma unroll
                for (int ky = 0; ky < 3; ++ky)
#pragma unroll
                    for (int kx = 0; kx < 3; ++kx)
                        a = fmaf(wp[ky * 3 + kx], p[ky][kx], a);
                acc[oc] = a;
            }
        }
    }

    const int y = tileY * 16 + ty, xx = tileX * 16 + tx;
    const int py = y >> 1, px = xx >> 1;
    const bool writer = !((tx & 1) | (ty & 1));
#pragma unroll
    for (int oc = 0; oc < 64; ++oc) {
        float v = fmaxf(acc[oc] + bias[oc], 0.f);
        v = fmaxf(v, __shfl_xor(v, 1));   // pool along x (pairs in-wave)
        v = fmaxf(v, __shfl_xor(v, 16));  // pool along y (row pairs in-wave)
        if (writer) out[((b * 64 + oc) * 128 + py) * 128 + px] = v;
    }
}

// ---------- Kernel C: fuse conv3x3 (128->128) + bias + relu + global mean ---
// in: s2_rgb (8,64,128,128) ++ s2_ir (8,64,128,128); out featsum: (8,128) sums.
__global__ __launch_bounds__(256) void fuse_mean(
    const float* __restrict__ inA, const float* __restrict__ inB,
    const float* __restrict__ w, const float* __restrict__ bias,
    float* __restrict__ featsum)
{
    __shared__ float s[2 * 324];
    __shared__ float partial[4 * 32];
    const int z = blockIdx.z;          // b*4 + ocg
    const int b = z >> 2, ocg = z & 3; // 32 output channels per group
    const int tileX = blockIdx.x, tileY = blockIdx.y;  // 16x16 conv pixels @128
    const int tid = threadIdx.x;
    const int tx = tid & 15, ty = tid >> 4;
    const int y0 = tileY * 16 - 1, x0 = tileX * 16 - 1;

    float acc[32];
#pragma unroll
    for (int oc = 0; oc < 32; ++oc) acc[oc] = 0.f;

    for (int ic = 0; ic < 128; ic += 2) {
        __syncthreads();
        for (int i = tid; i < 648; i += 256) {
            int sub = (i >= 324) ? 1 : 0;
            int r = i - sub * 324;
            int y = r / 18, xx = r % 18;
            int ih = y0 + y, iw = x0 + xx;
            int icl = ic + sub;
            const float* src = (icl < 64)
                ? &inA[(size_t)(b * 64 + icl) * 128 * 128]
                : &inB[(size_t)(b * 64 + icl - 64) * 128 * 128];
            float v = 0.f;
            if (ih >= 0 && ih < 128 && iw >= 0 && iw < 128)
                v = src[ih * 128 + iw];
            s[i] = v;
        }
        __syncthreads();

#pragma unroll
        for (int sub = 0; sub < 2; ++sub) {
            float p[3][3];
#pragma unroll
            for (int dy = 0; dy < 3; ++dy)
#pragma unroll
                for (int dx = 0; dx < 3; ++dx)
                    p[dy][dx] = s[sub * 324 + (ty + dy) * 18 + tx + dx];
#pragma unroll
            for (int oc = 0; oc < 32; ++oc) {
                const float* wp = &w[(((ocg * 32 + oc) * 128 + ic + sub) * 3) * 3];
                float a = acc[oc];
#pragma unroll
                for (int ky = 0; ky < 3; ++ky)
#pragma unroll
                    for (int kx = 0; kx < 3; ++kx)
                        a = fmaf(wp[ky * 3 + kx], p[ky][kx], a);
                acc[oc] = a;
            }
        }
    }

    // bias + relu, then reduce over the 256 pixels of this tile
    const int lane = tid & 63, wid = tid >> 6;
#pragma unroll
    for (int oc = 0; oc < 32; ++oc) {
        float v = fmaxf(acc[oc] + bias[ocg * 32 + oc], 0.f);
        v += __shfl_xor(v, 1);
        v += __shfl_xor(v, 2);
        v += __shfl_xor(v, 4);
        v += __shfl_xor(v, 8);
        v += __shfl_xor(v, 16);
        v += __shfl_xor(v, 32);
        if (lane == 0) partial[wid * 32 + oc] = v;
    }
    __syncthreads();
    if (tid < 32) {
        float v = partial[tid] + partial[32 + tid] + partial[64 + tid] + partial[96 + tid];
        atomicAdd(&featsum[b * 128 + ocg * 32 + tid], v);
    }
}

// ---------- Kernel D: det head + sigmoid + NMS + outputs --------------------
__global__ void det_nms(const float* __restrict__ featsum,
                        const float* __restrict__ dw, const float* __restrict__ db,
                        float* __restrict__ out)
{
    const int b = threadIdx.x;
    if (b >= 8) return;
    const float inv = 1.0f / 16384.0f;

    float p[18];
    for (int j = 0; j < 18; ++j) {
        float a = db[j];
        const float* wp = &dw[j * 128];
        const float* f = &featsum[b * 128];
        for (int c = 0; c < 128; ++c) a = fmaf(wp[c], f[c] * inv, a);
        p[j] = a;
    }
    // p: (8,3,1,1,6) flat
    for (int a = 0; a < 3; ++a)
        for (int e = 0; e < 6; ++e) out[b * 18 + a * 6 + e] = p[a * 6 + e];

    float bx[3][4], sc[3];
    bool ck[3];
    for (int a = 0; a < 3; ++a) {
        for (int k = 0; k < 4; ++k) {
            bx[a][k] = p[a * 6 + k];
            out[144 + b * 12 + a * 4 + k] = bx[a][k];
        }
        float sg = 1.f / (1.f + expf(-p[a * 6 + 4]));
        sc[a] = sg;
        ck[a] = sg > 0.5f;
        out[240 + b * 3 + a] = sg;
    }

    // stable descending argsort of (conf_keep ? score : -inf)
    float key[3];
    int order[3];
    bool used[3] = {false, false, false};
    for (int a = 0; a < 3; ++a) key[a] = ck[a] ? sc[a] : -INFINITY;
    for (int i = 0; i < 3; ++i) {
        int best = -1;
        float bk = 0.f;
        for (int a = 0; a < 3; ++a) {
            if (used[a]) continue;
            if (best < 0 || key[a] > bk) { best = a; bk = key[a]; }
        }
        order[i] = best;
        used[best] = true;
    }

    float X1[3], Y1[3], X2[3], Y2[3], AR[3];
    for (int i = 0; i < 3; ++i) {
        int o = order[i];
        X1[i] = bx[o][0]; Y1[i] = bx[o][1];
        X2[i] = bx[o][2]; Y2[i] = bx[o][3];
        AR[i] = (X2[i] - X1[i]) * (Y2[i] - Y1[i]);
    }
    bool suppressed[3] = {false, false, false}, keep_s[3];
    for (int i = 0; i < 3; ++i) {
        bool valid = !suppressed[i];
        keep_s[i] = valid;
        if (valid) {
            for (int j = i + 1; j < 3; ++j) {
                float ix1 = fmaxf(X1[i], X1[j]), iy1 = fmaxf(Y1[i], Y1[j]);
                float ix2 = fminf(X2[i], X2[j]), iy2 = fminf(Y2[i], Y2[j]);
                float inter = fmaxf(ix2 - ix1, 0.f) * fmaxf(iy2 - iy1, 0.f);
                float iou = inter / (AR[i] + AR[j] - inter);
                if (iou > 0.5f) suppressed[j] = true;  // NaN compares false, like jnp
            }
        }
    }
    bool keep[3];
    for (int i = 0; i < 3; ++i) keep[order[i]] = keep_s[i];
    for (int a = 0; a < 3; ++a)
        out[264 + b * 3 + a] = (keep[a] && ck[a]) ? 1.f : 0.f;
}

__global__ void zero_feat(float* __restrict__ p)
{
    int i = blockIdx.x * 256 + threadIdx.x;
    if (i < 1024) p[i] = 0.f;
}

// ---------------------------------------------------------------------------
extern "C" void kernel_launch(void* const* d_in, const int* in_sizes, int n_in,
                              void* d_out, int out_size, void* d_ws, size_t ws_size,
                              hipStream_t stream)
{
    const float* x      = (const float*)d_in[0];
    const float* rgb_w1 = (const float*)d_in[1];
    const float* rgb_b1 = (const float*)d_in[2];
    const float* rgb_w2 = (const float*)d_in[3];
    const float* rgb_b2 = (const float*)d_in[4];
    const float* ir_w1  = (const float*)d_in[5];
    const float* ir_b1  = (const float*)d_in[6];
    const float* ir_w2  = (const float*)d_in[7];
    const float* ir_b2  = (const float*)d_in[8];
    const float* fuse_w = (const float*)d_in[9];
    const float* fuse_b = (const float*)d_in[10];
    const float* det_w  = (const float*)d_in[11];
    const float* det_b  = (const float*)d_in[12];
    float* out = (float*)d_out;

    char* ws = (char*)d_ws;
    float* s1   = (float*)(ws);                               // 67,108,864 B
    float* s2r  = (float*)(ws + 67108864);                    // 33,554,432 B
    float* s2i  = (float*)(ws + 67108864 + 33554432);         // 33,554,432 B
    float* feat = (float*)(ws + 67108864 + 2 * 33554432);     // 4,096 B

    dim3 blk(256);
    hipLaunchKernelGGL(zero_feat, dim3(4), blk, 0, stream, feat);
    // s1 reused between streams (serialized on the stream)
    hipLaunchKernelGGL(conv1_pool, dim3(16, 16, 8), blk, 0, stream, x, rgb_w1, rgb_b1, s1);
    hipLaunchKernelGGL(conv2_pool, dim3(16, 16, 8), blk, 0, stream, s1, rgb_w2, rgb_b2, s2r);
    hipLaunchKernelGGL(conv1_pool, dim3(16, 16, 8), blk, 0, stream, x, ir_w1, ir_b1, s1);
    hipLaunchKernelGGL(conv2_pool, dim3(16, 16, 8), blk, 0, stream, s1, ir_w2, ir_b2, s2i);
    hipLaunchKernelGGL(fuse_mean, dim3(8, 8, 32), blk, 0, stream, s2r, s2i, fuse_w, fuse_b, feat);
    hipLaunchKernelGGL(det_nms, dim3(1), dim3(64), 0, stream, feat, det_w, det_b, out);
}

// Round 2
// 1071.206 us; speedup vs baseline: 3.2165x; 3.2165x over previous
//
#include <hip/hip_runtime.h>
#include <math.h>

// ---------------------------------------------------------------------------
// MultiStreamCNN: two conv streams (3->32->64 w/ relu+maxpool2), concat,
// fuse conv 3x3 (128->128) + relu + global mean, det 1x1 conv, sigmoid + NMS.
// All fp32 (no fp32-input MFMA on CDNA4; bf16 risks the binary `keep` output).
//
// R2: conv2/fuse restructured to 2x2 pixels/thread (4 FMA per weight dword,
// scalar-pipe latency amortized) + register-prefetch double-buffered LDS
// staging (1 barrier per ic, global latency hidden behind compute).
// ---------------------------------------------------------------------------

// ---------- Kernel A: conv3x3 (3->32) + bias + relu + maxpool2 --------------
// in x: (8,3,512,512), out: (8,32,256,256). Block = 16x16 pooled pixels.
__global__ __launch_bounds__(256) void conv1_pool(
    const float* __restrict__ x, const float* __restrict__ w,
    const float* __restrict__ bias, float* __restrict__ out)
{
    __shared__ float s[3 * 34 * 34];
    const int b = blockIdx.z;
    const int tileX = blockIdx.x, tileY = blockIdx.y;
    const int tid = threadIdx.x;
    const int tx = tid & 15, ty = tid >> 4;
    const int ih0 = tileY * 32 - 1, iw0 = tileX * 32 - 1;

    for (int i = tid; i < 3 * 34 * 34; i += 256) {
        int c = i / 1156, r = i % 1156;
        int y = r / 34, xx = r % 34;
        int ih = ih0 + y, iw = iw0 + xx;
        float v = 0.f;
        if (ih >= 0 && ih < 512 && iw >= 0 && iw < 512)
            v = x[((b * 3 + c) * 512 + ih) * 512 + iw];
        s[i] = v;
    }
    __syncthreads();

    float in[3][4][4];
#pragma unroll
    for (int c = 0; c < 3; ++c)
#pragma unroll
        for (int dy = 0; dy < 4; ++dy)
#pragma unroll
            for (int dx = 0; dx < 4; ++dx)
                in[c][dy][dx] = s[c * 1156 + (2 * ty + dy) * 34 + (2 * tx + dx)];

    const int oh = tileY * 16 + ty, ow = tileX * 16 + tx;
    for (int oc = 0; oc < 32; ++oc) {
        const float bv = bias[oc];
        float m = -INFINITY;
#pragma unroll
        for (int py = 0; py < 2; ++py)
#pragma unroll
            for (int px = 0; px < 2; ++px) {
                float a = 0.f;
#pragma unroll
                for (int c = 0; c < 3; ++c)
#pragma unroll
                    for (int ky = 0; ky < 3; ++ky)
#pragma unroll
                        for (int kx = 0; kx < 3; ++kx)
                            a = fmaf(w[((oc * 3 + c) * 3 + ky) * 3 + kx],
                                     in[c][py + ky][px + kx], a);
                m = fmaxf(m, a);
            }
        m = fmaxf(m + bv, 0.f);  // bias uniform over window; relu after max ok
        out[((b * 32 + oc) * 256 + oh) * 256 + ow] = m;
    }
}

// ---------- Kernel B: conv3x3 (32->64) + bias + relu + maxpool2 -------------
// in: (8,32,256,256), out: (8,64,128,128).
// Block: 16x16 POOLED px (= 32x32 conv px), 16 oc per block (z = b*4+ocg).
// Each thread computes its pooled pixel's 2x2 conv window and pools in-thread.
__global__ __launch_bounds__(256) void conv2_pool(
    const float* __restrict__ in, const float* __restrict__ w,
    const float* __restrict__ bias, float* __restrict__ out)
{
    __shared__ float sb[2][34 * 34];
    const int z = blockIdx.z, b = z >> 2, ocg = z & 3;
    const int tid = threadIdx.x, tx = tid & 15, ty = tid >> 4;
    const int cy0 = blockIdx.y * 32 - 1, cx0 = blockIdx.x * 32 - 1;

    // precomputed staging slots (ic-invariant): i = tid + 256k over 34x34 halo
    int off_[5]; float msk_[5];
#pragma unroll
    for (int k = 0; k < 5; ++k) {
        int i = tid + k * 256;
        int y = i / 34, xx = i - y * 34;
        int ih = cy0 + y, iw = cx0 + xx;
        bool ok = (i < 1156) & (ih >= 0) & (ih < 256) & (iw >= 0) & (iw < 256);
        off_[k] = ok ? ih * 256 + iw : 0;
        msk_[k] = ok ? 1.f : 0.f;
    }

    float r_[5];
    {
        const float* base = in + ((size_t)(b * 32) << 16);
#pragma unroll
        for (int k = 0; k < 5; ++k) r_[k] = base[off_[k]] * msk_[k];
    }

    float acc[16][2][2];
#pragma unroll
    for (int oc = 0; oc < 16; ++oc)
#pragma unroll
        for (int i = 0; i < 4; ++i) acc[oc][i >> 1][i & 1] = 0.f;

    for (int ic = 0; ic < 32; ++ic) {
        float* s = sb[ic & 1];
#pragma unroll
        for (int k = 0; k < 5; ++k) {
            int i = tid + k * 256;
            if (i < 1156) s[i] = r_[k];
        }
        __syncthreads();
        if (ic + 1 < 32) {  // prefetch next ic into regs; consumed next iter
            const float* nb = in + ((size_t)(b * 32 + ic + 1) << 16);
#pragma unroll
            for (int k = 0; k < 5; ++k) r_[k] = nb[off_[k]] * msk_[k];
        }
        float p[4][4];
#pragma unroll
        for (int dy = 0; dy < 4; ++dy)
#pragma unroll
            for (int dx = 0; dx < 4; ++dx)
                p[dy][dx] = s[(2 * ty + dy) * 34 + 2 * tx + dx];
        const float* wic = &w[((ocg * 16) * 32 + ic) * 9];
#pragma unroll
        for (int oc = 0; oc < 16; ++oc) {
            const float* wo = wic + oc * (32 * 9);
#pragma unroll
            for (int py = 0; py < 2; ++py)
#pragma unroll
                for (int px = 0; px < 2; ++px) {
                    float a = acc[oc][py][px];
#pragma unroll
                    for (int ky = 0; ky < 3; ++ky)
#pragma unroll
                        for (int kx = 0; kx < 3; ++kx)
                            a = fmaf(wo[ky * 3 + kx], p[py + ky][px + kx], a);
                    acc[oc][py][px] = a;
                }
        }
        // no trailing barrier: next iter writes the other LDS buffer
    }

    const int pooly = blockIdx.y * 16 + ty, poolx = blockIdx.x * 16 + tx;
#pragma unroll
    for (int oc = 0; oc < 16; ++oc) {
        float bv = bias[ocg * 16 + oc];
        float m = fmaxf(fmaxf(acc[oc][0][0], acc[oc][0][1]),
                        fmaxf(acc[oc][1][0], acc[oc][1][1]));
        m = fmaxf(m + bv, 0.f);
        out[((size_t)(b * 64 + ocg * 16 + oc) * 128 + pooly) * 128 + poolx] = m;
    }
}

// ---------- Kernel C: fuse conv3x3 (128->128) + bias + relu + global mean ---
// in: s2_rgb (8,64,128,128) ++ s2_ir (8,64,128,128); out featsum: (8,128) sums.
// Block: 32x32 conv px tile (2x2 per thread), 16 oc per block (z = b*8+ocg).
__global__ __launch_bounds__(256) void fuse_mean(
    const float* __restrict__ inA, const float* __restrict__ inB,
    const float* __restrict__ w, const float* __restrict__ bias,
    float* __restrict__ featsum)
{
    __shared__ float sb[2][34 * 34];
    __shared__ float partial[4][16];
    const int z = blockIdx.z, b = z >> 3, ocg = z & 7;
    const int tid = threadIdx.x, tx = tid & 15, ty = tid >> 4;
    const int cy0 = blockIdx.y * 32 - 1, cx0 = blockIdx.x * 32 - 1;

    int off_[5]; float msk_[5];
#pragma unroll
    for (int k = 0; k < 5; ++k) {
        int i = tid + k * 256;
        int y = i / 34, xx = i - y * 34;
        int ih = cy0 + y, iw = cx0 + xx;
        bool ok = (i < 1156) & (ih >= 0) & (ih < 128) & (iw >= 0) & (iw < 128);
        off_[k] = ok ? ih * 128 + iw : 0;
        msk_[k] = ok ? 1.f : 0.f;
    }

    float r_[5];
    {
        const float* base = inA + ((size_t)(b * 64) << 14);
#pragma unroll
        for (int k = 0; k < 5; ++k) r_[k] = base[off_[k]] * msk_[k];
    }

    float acc[16][2][2];
#pragma unroll
    for (int oc = 0; oc < 16; ++oc)
#pragma unroll
        for (int i = 0; i < 4; ++i) acc[oc][i >> 1][i & 1] = 0.f;

    for (int ic = 0; ic < 128; ++ic) {
        float* s = sb[ic & 1];
#pragma unroll
        for (int k = 0; k < 5; ++k) {
            int i = tid + k * 256;
            if (i < 1156) s[i] = r_[k];
        }
        __syncthreads();
        if (ic + 1 < 128) {
            int icn = ic + 1;
            const float* nb = (icn < 64)
                ? inA + ((size_t)(b * 64 + icn) << 14)
                : inB + ((size_t)(b * 64 + icn - 64) << 14);
#pragma unroll
            for (int k = 0; k < 5; ++k) r_[k] = nb[off_[k]] * msk_[k];
        }
        float p[4][4];
#pragma unroll
        for (int dy = 0; dy < 4; ++dy)
#pragma unroll
            for (int dx = 0; dx < 4; ++dx)
                p[dy][dx] = s[(2 * ty + dy) * 34 + 2 * tx + dx];
        const float* wic = &w[((ocg * 16) * 128 + ic) * 9];
#pragma unroll
        for (int oc = 0; oc < 16; ++oc) {
            const float* wo = wic + oc * (128 * 9);
#pragma unroll
            for (int py = 0; py < 2; ++py)
#pragma unroll
                for (int px = 0; px < 2; ++px) {
                    float a = acc[oc][py][px];
#pragma unroll
                    for (int ky = 0; ky < 3; ++ky)
#pragma unroll
                        for (int kx = 0; kx < 3; ++kx)
                            a = fmaf(wo[ky * 3 + kx], p[py + ky][px + kx], a);
                    acc[oc][py][px] = a;
                }
        }
    }

    const int lane = tid & 63, wid = tid >> 6;
#pragma unroll
    for (int oc = 0; oc < 16; ++oc) {
        float bv = bias[ocg * 16 + oc];
        float v = fmaxf(acc[oc][0][0] + bv, 0.f) + fmaxf(acc[oc][0][1] + bv, 0.f)
                + fmaxf(acc[oc][1][0] + bv, 0.f) + fmaxf(acc[oc][1][1] + bv, 0.f);
        v += __shfl_xor(v, 1);
        v += __shfl_xor(v, 2);
        v += __shfl_xor(v, 4);
        v += __shfl_xor(v, 8);
        v += __shfl_xor(v, 16);
        v += __shfl_xor(v, 32);
        if (lane == 0) partial[wid][oc] = v;
    }
    __syncthreads();
    if (tid < 16) {
        float v = partial[0][tid] + partial[1][tid] + partial[2][tid] + partial[3][tid];
        atomicAdd(&featsum[b * 128 + ocg * 16 + tid], v);
    }
}

// ---------- Kernel D: det head + sigmoid + NMS + outputs --------------------
__global__ void det_nms(const float* __restrict__ featsum,
                        const float* __restrict__ dw, const float* __restrict__ db,
                        float* __restrict__ out)
{
    const int b = threadIdx.x;
    if (b >= 8) return;
    const float inv = 1.0f / 16384.0f;

    float p[18];
    for (int j = 0; j < 18; ++j) {
        float a = db[j];
        const float* wp = &dw[j * 128];
        const float* f = &featsum[b * 128];
        for (int c = 0; c < 128; ++c) a = fmaf(wp[c], f[c] * inv, a);
        p[j] = a;
    }
    for (int a = 0; a < 3; ++a)
        for (int e = 0; e < 6; ++e) out[b * 18 + a * 6 + e] = p[a * 6 + e];

    float bx[3][4], sc[3];
    bool ck[3];
    for (int a = 0; a < 3; ++a) {
        for (int k = 0; k < 4; ++k) {
            bx[a][k] = p[a * 6 + k];
            out[144 + b * 12 + a * 4 + k] = bx[a][k];
        }
        float sg = 1.f / (1.f + expf(-p[a * 6 + 4]));
        sc[a] = sg;
        ck[a] = sg > 0.5f;
        out[240 + b * 3 + a] = sg;
    }

    float key[3];
    int order[3];
    bool used[3] = {false, false, false};
    for (int a = 0; a < 3; ++a) key[a] = ck[a] ? sc[a] : -INFINITY;
    for (int i = 0; i < 3; ++i) {
        int best = -1;
        float bk = 0.f;
        for (int a = 0; a < 3; ++a) {
            if (used[a]) continue;
            if (best < 0 || key[a] > bk) { best = a; bk = key[a]; }
        }
        order[i] = best;
        used[best] = true;
    }

    float X1[3], Y1[3], X2[3], Y2[3], AR[3];
    for (int i = 0; i < 3; ++i) {
        int o = order[i];
        X1[i] = bx[o][0]; Y1[i] = bx[o][1];
        X2[i] = bx[o][2]; Y2[i] = bx[o][3];
        AR[i] = (X2[i] - X1[i]) * (Y2[i] - Y1[i]);
    }
    bool suppressed[3] = {false, false, false}, keep_s[3];
    for (int i = 0; i < 3; ++i) {
        bool valid = !suppressed[i];
        keep_s[i] = valid;
        if (valid) {
            for (int j = i + 1; j < 3; ++j) {
                float ix1 = fmaxf(X1[i], X1[j]), iy1 = fmaxf(Y1[i], Y1[j]);
                float ix2 = fminf(X2[i], X2[j]), iy2 = fminf(Y2[i], Y2[j]);
                float inter = fmaxf(ix2 - ix1, 0.f) * fmaxf(iy2 - iy1, 0.f);
                float iou = inter / (AR[i] + AR[j] - inter);
                if (iou > 0.5f) suppressed[j] = true;  // NaN compares false, like jnp
            }
        }
    }
    bool keep[3];
    for (int i = 0; i < 3; ++i) keep[order[i]] = keep_s[i];
    for (int a = 0; a < 3; ++a)
        out[264 + b * 3 + a] = (keep[a] && ck[a]) ? 1.f : 0.f;
}

__global__ void zero_feat(float* __restrict__ p)
{
    int i = blockIdx.x * 256 + threadIdx.x;
    if (i < 1024) p[i] = 0.f;
}

// ---------------------------------------------------------------------------
extern "C" void kernel_launch(void* const* d_in, const int* in_sizes, int n_in,
                              void* d_out, int out_size, void* d_ws, size_t ws_size,
                              hipStream_t stream)
{
    const float* x      = (const float*)d_in[0];
    const float* rgb_w1 = (const float*)d_in[1];
    const float* rgb_b1 = (const float*)d_in[2];
    const float* rgb_w2 = (const float*)d_in[3];
    const float* rgb_b2 = (const float*)d_in[4];
    const float* ir_w1  = (const float*)d_in[5];
    const float* ir_b1  = (const float*)d_in[6];
    const float* ir_w2  = (const float*)d_in[7];
    const float* ir_b2  = (const float*)d_in[8];
    const float* fuse_w = (const float*)d_in[9];
    const float* fuse_b = (const float*)d_in[10];
    const float* det_w  = (const float*)d_in[11];
    const float* det_b  = (const float*)d_in[12];
    float* out = (float*)d_out;

    char* ws = (char*)d_ws;
    float* s1   = (float*)(ws);                               // 67,108,864 B
    float* s2r  = (float*)(ws + 67108864);                    // 33,554,432 B
    float* s2i  = (float*)(ws + 67108864 + 33554432);         // 33,554,432 B
    float* feat = (float*)(ws + 67108864 + 2 * 33554432);     // 4,096 B

    dim3 blk(256);
    hipLaunchKernelGGL(zero_feat, dim3(4), blk, 0, stream, feat);
    // s1 reused between streams (serialized on the stream)
    hipLaunchKernelGGL(conv1_pool, dim3(16, 16, 8), blk, 0, stream, x, rgb_w1, rgb_b1, s1);
    hipLaunchKernelGGL(conv2_pool, dim3(8, 8, 32), blk, 0, stream, s1, rgb_w2, rgb_b2, s2r);
    hipLaunchKernelGGL(conv1_pool, dim3(16, 16, 8), blk, 0, stream, x, ir_w1, ir_b1, s1);
    hipLaunchKernelGGL(conv2_pool, dim3(8, 8, 32), blk, 0, stream, s1, ir_w2, ir_b2, s2i);
    hipLaunchKernelGGL(fuse_mean, dim3(4, 4, 64), blk, 0, stream, s2r, s2i, fuse_w, fuse_b, feat);
    hipLaunchKernelGGL(det_nms, dim3(1), dim3(64), 0, stream, feat, det_w, det_b, out);
}